// Round 10
// baseline (11027.125 us; speedup 1.0000x reference)
//
#include <hip/hip_runtime.h>
#include <stdint.h>

// ST_BLOCK fused, R10: R7 step body (best measured: B staged via global_load_lds,
// kk-split 3x2 wave tile, setprio, counted vmcnt) + h ping-pong (race fix) +
// XCD-clustered bijective block swizzle (each XCD owns 8bb x 8qt: per-XCD A 3.1MB
// + B 2MB ~ L2-resident, vs 6.3MB A thrash before) + reps=8 probe dispatch so the
// step body's counters appear in rocprof top-5.

#define Bb   16
#define CIN  32
#define COUT 64
#define Nn   1024
#define Tt   64
#define Ff   96
#define G4   256
#define KJ   288

#define BUFSZ 40960     // A hi 12K | A lo 12K | B hi 8K | B lo 8K
#define GQPB  624       // Gq row pitch bytes (312 u16)
#define GQLO  19968     // Gq_lo offset (32*624)
#define SCP   100       // merge scratch pitch (floats); scratch at lds+BUFSZ

typedef unsigned short u16;
typedef short short8 __attribute__((ext_vector_type(8)));
typedef short short4v __attribute__((ext_vector_type(4)));
typedef float f32x4 __attribute__((ext_vector_type(4)));

static __device__ __forceinline__ u16 f2bf(float f) {
    union { float f; uint32_t u; } v; v.f = f;
    uint32_t r = v.u + 0x7FFFu + ((v.u >> 16) & 1u);
    return (u16)(r >> 16);
}
static __device__ __forceinline__ float bf2f(u16 h) {
    union { uint32_t u; float f; } v; v.u = ((uint32_t)h) << 16;
    return v.f;
}
static __device__ __forceinline__ float sigm(float x) { return 1.0f / (1.0f + expf(-x)); }

static __device__ __forceinline__ void gload16(const void* g, void* l) {
    __builtin_amdgcn_global_load_lds(
        (const __attribute__((address_space(1))) void*)g,
        (__attribute__((address_space(3))) void*)l, 16, 0, 0);
}

// ---------------- diagnostics ----------------
__global__ void k_fill(float* out, int n, float v) {
    int i = blockIdx.x * 256 + threadIdx.x;
    if (i < n) out[i] = v;
}

// ---------------- P0: adj -> bcat rows 0..1023 ----------------
__global__ __launch_bounds__(256) void k_adj_split(const float* __restrict__ adj,
                                                   u16* __restrict__ hi, u16* __restrict__ lo) {
    int i = blockIdx.x * 256 + threadIdx.x;
    float v = adj[i];
    u16 h = f2bf(v);
    hi[i] = h; lo[i] = f2bf(v - bf2f(h));
}

// ---------------- P0b: adjT split ----------------
__global__ __launch_bounds__(256) void k_adj_t(const float* __restrict__ adj,
                                               u16* __restrict__ th, u16* __restrict__ tl_) {
    __shared__ float tile[64][65];
    int m0 = blockIdx.x * 64, n0 = blockIdx.y * 64;
    int tid = threadIdx.x;
    #pragma unroll
    for (int i = 0; i < 16; i++) {
        int lin = i * 256 + tid;
        int ml = lin >> 6, nl = lin & 63;
        tile[ml][nl] = adj[(size_t)(m0 + ml) * Nn + n0 + nl];
    }
    __syncthreads();
    #pragma unroll
    for (int i = 0; i < 16; i++) {
        int lin = i * 256 + tid;
        int nl = lin >> 6, ml = lin & 63;
        float v = tile[ml][nl];
        u16 h = f2bf(v);
        size_t off = (size_t)(n0 + nl) * Nn + m0 + ml;
        th[off] = h; tl_[off] = f2bf(v - bf2f(h));
    }
}

// ---------------- P0c: L2 = 2*adj@adj - I -> bcat rows 1024+ ----------------
__global__ __launch_bounds__(256) void k_l2(
    const u16* __restrict__ a_hi, const u16* __restrict__ a_lo,
    const u16* __restrict__ bt_hi, const u16* __restrict__ bt_lo,
    u16* __restrict__ o_hi, u16* __restrict__ o_lo)
{
    __shared__ u16 Ah[64][40], Al[64][40], Bh[64][40], Bl[64][40];
    const int tid = threadIdx.x, lane = tid & 63, w = tid >> 6;
    const int wm = (w >> 1) * 32, wn = (w & 1) * 32;
    const int r0 = blockIdx.x * 64, q0 = blockIdx.y * 64;
    const int srow = tid >> 2, scol = (tid & 3) * 8;
    const u16* arh = a_hi + (size_t)(r0 + srow) * Nn;
    const u16* arl = a_lo + (size_t)(r0 + srow) * Nn;
    const u16* brh = bt_hi + (size_t)(q0 + srow) * Nn;
    const u16* brl = bt_lo + (size_t)(q0 + srow) * Nn;

    f32x4 acc[2][2];
    #pragma unroll
    for (int i = 0; i < 2; i++)
        #pragma unroll
        for (int j = 0; j < 2; j++) acc[i][j] = (f32x4){0.f, 0.f, 0.f, 0.f};

    for (int k0 = 0; k0 < Nn; k0 += 32) {
        __syncthreads();
        *(short8*)&Ah[srow][scol] = *(const short8*)&arh[k0 + scol];
        *(short8*)&Al[srow][scol] = *(const short8*)&arl[k0 + scol];
        *(short8*)&Bh[srow][scol] = *(const short8*)&brh[k0 + scol];
        *(short8*)&Bl[srow][scol] = *(const short8*)&brl[k0 + scol];
        __syncthreads();
        const int kb = (lane >> 4) * 8;
        short8 ah[2], al[2], bh[2], bl[2];
        #pragma unroll
        for (int mi = 0; mi < 2; mi++) {
            int row = wm + mi * 16 + (lane & 15);
            ah[mi] = *(const short8*)&Ah[row][kb];
            al[mi] = *(const short8*)&Al[row][kb];
        }
        #pragma unroll
        for (int ni = 0; ni < 2; ni++) {
            int col = wn + ni * 16 + (lane & 15);
            bh[ni] = *(const short8*)&Bh[col][kb];
            bl[ni] = *(const short8*)&Bl[col][kb];
        }
        #pragma unroll
        for (int mi = 0; mi < 2; mi++)
            #pragma unroll
            for (int ni = 0; ni < 2; ni++) {
                acc[mi][ni] = __builtin_amdgcn_mfma_f32_16x16x32_bf16(ah[mi], bh[ni], acc[mi][ni], 0, 0, 0);
                acc[mi][ni] = __builtin_amdgcn_mfma_f32_16x16x32_bf16(al[mi], bh[ni], acc[mi][ni], 0, 0, 0);
                acc[mi][ni] = __builtin_amdgcn_mfma_f32_16x16x32_bf16(ah[mi], bl[ni], acc[mi][ni], 0, 0, 0);
            }
    }
    #pragma unroll
    for (int mi = 0; mi < 2; mi++)
        #pragma unroll
        for (int ni = 0; ni < 2; ni++)
            #pragma unroll
            for (int j = 0; j < 4; j++) {
                int rr = r0 + wm + mi * 16 + (lane >> 4) * 4 + j;
                int qq = q0 + wn + ni * 16 + (lane & 15);
                float v = 2.f * acc[mi][ni][j] - ((rr == qq) ? 1.f : 0.f);
                size_t off = (size_t)rr * Nn + qq;
                u16 hh = f2bf(v);
                o_hi[off] = hh; o_lo[off] = f2bf(v - bf2f(hh));
            }
}

// ---------------- P2: W reorder+split ----------------
__global__ __launch_bounds__(256) void k_w_split(const float* __restrict__ W,
                                                 u16* __restrict__ hi, u16* __restrict__ lo) {
    int idx = blockIdx.x * 256 + threadIdx.x;
    int o = idx / KJ, j = idx - o * KJ;
    int k = j / Ff, f = j - k * Ff;
    float v = W[(size_t)o * KJ + f * 3 + k];
    u16 h = f2bf(v);
    hi[idx] = h; lo[idx] = f2bf(v - bf2f(h));
}

// ---------------- P1: x (B,CIN,N,T) -> xsf (T,B,CIN,N) split, vectorized stores ----------------
__global__ __launch_bounds__(256) void k_x_split(const float* __restrict__ x,
        u16* __restrict__ xf_hi, u16* __restrict__ xf_lo) {
    __shared__ float tile[64][65];
    int n0 = blockIdx.x * 64;
    int bc = blockIdx.y;
    const float* src = x + (size_t)bc * Nn * Tt;
    int tid = threadIdx.x;
    #pragma unroll
    for (int i = 0; i < 16; i++) {
        int lin = i * 256 + tid;
        int nl = lin >> 6, tl = lin & 63;
        tile[nl][tl] = src[(size_t)(n0 + nl) * Tt + tl];
    }
    __syncthreads();
    int b = bc >> 5, ch = bc & 31;
    #pragma unroll
    for (int i = 0; i < 2; i++) {
        int item = i * 256 + tid;
        int tl = item >> 3, oct = item & 7;
        short8 vh, vl;
        #pragma unroll
        for (int m = 0; m < 8; m++) {
            float v = tile[oct * 8 + m][tl];
            u16 h = f2bf(v);
            vh[m] = (short)h;
            vl[m] = (short)f2bf(v - bf2f(h));
        }
        size_t off = (((size_t)tl * Bb + b) * CIN + ch) * Nn + n0 + oct * 8;
        *(short8*)&xf_hi[off] = vh;
        *(short8*)&xf_lo[off] = vl;
    }
}

// ---------------- K: fused step ----------------
// 1D grid 512 blocks, 512 threads, LDS 81920 -> 2 blocks/CU.
// XCD-clustered decode: xcd = bid&7 owns bb in {8*(xcd&1)..+8}, qt in {8*(xcd>>1)..+8}.
__global__ __launch_bounds__(512, 4) void k_step(
    int t, int reps,
    const u16* __restrict__ xsf_hi, const u16* __restrict__ xsf_lo,
    const u16* __restrict__ hin_hi, const u16* __restrict__ hin_lo,
    u16* __restrict__ hout_hi, u16* __restrict__ hout_lo,
    const u16* __restrict__ bcat_hi, const u16* __restrict__ bcat_lo,
    const u16* __restrict__ Wh, const u16* __restrict__ Wl,
    const float* __restrict__ bias, float* __restrict__ cbuf,
    float* __restrict__ outbuf)
{
    __shared__ __attribute__((aligned(16))) char lds[81920];
    const int tid = threadIdx.x, lane = tid & 63, w = tid >> 6;
    const int bid = blockIdx.x;
    const int xcd = bid & 7, slot = bid >> 3;
    const int bb = ((xcd & 1) << 3) | (slot & 7);          // 0..15
    const int qt = ((xcd >> 1) << 3) | (slot >> 3);        // 0..31
    const int q0g = qt * 32;

    // ----- staging decode: 5 x 16B global_load_lds per thread per chunk -----
    // units: [0,768)=A_hi 96x8, [768,1536)=A_lo, [1536,2048)=B_hi 64x8, [2048,2560)=B_lo
    const u16* srcb[5];
    #pragma unroll
    for (int i = 0; i < 5; i++) {
        int u = i * 512 + tid;
        if (u < 1536) {
            int hl = (u >= 768) ? 1 : 0;
            int r = (u - hl * 768) >> 3, c8 = u & 7;
            const u16* p;
            if (r < CIN) p = (hl ? xsf_lo : xsf_hi) + (size_t)((t * Bb + bb) * CIN + r) * Nn;
            else         p = (hl ? hin_lo : hin_hi) + (size_t)(bb * COUT + r - CIN) * Nn;
            srcb[i] = p + (c8 ^ (r & 7)) * 8;
        } else {
            int v = u - 1536;
            int hl = v >> 9;
            int r = (v & 511) >> 3, c8 = v & 7;
            int grow = q0g + (r & 31) + ((r >= 32) ? Nn : 0);   // 0..31 adj, 32..63 L2
            srcb[i] = (hl ? bcat_lo : bcat_hi) + (size_t)grow * Nn + (c8 ^ (r & 7)) * 8;
        }
    }

    // phase-1 wave decomposition: kk-split (2 groups x 3x2 wave tile over 96x64)
    const int kg = w >> 2;
    const int wsub = w & 3;
    const int wr = wsub >> 1, wc = wsub & 1;
    const int ksw = kg * 4 + (lane >> 4);
    const int capkc = qt >> 1;

    for (int rep = 0; rep < reps; rep++) {
        f32x4 acc[3][2];
        #pragma unroll
        for (int i = 0; i < 3; i++)
            #pragma unroll
            for (int j = 0; j < 2; j++) acc[i][j] = (f32x4){0.f, 0.f, 0.f, 0.f};

        u16 cxh[6], cxl[6];
        #pragma unroll
        for (int i = 0; i < 6; i++) { cxh[i] = 0; cxl[i] = 0; }

        // prologue: chunk 0 -> buf0
        #pragma unroll
        for (int i = 0; i < 5; i++)
            gload16(srcb[i], lds + (i * 512 + tid) * 16);

        for (int kc = 0; kc < 16; kc++) {
            if (kc < 15) {
                char* nb = lds + ((kc + 1) & 1) * BUFSZ;
                const int k0 = (kc + 1) * 64;
                #pragma unroll
                for (int i = 0; i < 5; i++)
                    gload16(srcb[i] + k0, nb + (i * 512 + tid) * 16);
                asm volatile("s_waitcnt vmcnt(5)" ::: "memory");
            } else {
                asm volatile("s_waitcnt vmcnt(0)" ::: "memory");
            }
            __builtin_amdgcn_s_barrier();
            const char* bo = lds + (kc & 1) * BUFSZ;
            {
                short8 ah[3], al[3], bh[2], bl[2];
                #pragma unroll
                for (int mi = 0; mi < 3; mi++) {
                    int r = wr * 48 + mi * 16 + (lane & 15);
                    int off = r * 128 + ((ksw ^ (r & 7)) << 4);
                    ah[mi] = *(const short8*)(bo + off);
                    al[mi] = *(const short8*)(bo + 12288 + off);
                }
                #pragma unroll
                for (int ni = 0; ni < 2; ni++) {
                    int rb = wc * 32 + ni * 16 + (lane & 15);
                    int off = 24576 + rb * 128 + ((ksw ^ (rb & 7)) << 4);
                    bh[ni] = *(const short8*)(bo + off);
                    bl[ni] = *(const short8*)(bo + 8192 + off);
                }
                __builtin_amdgcn_s_setprio(1);
                #pragma unroll
                for (int mi = 0; mi < 3; mi++)
                    #pragma unroll
                    for (int ni = 0; ni < 2; ni++) {
                        acc[mi][ni] = __builtin_amdgcn_mfma_f32_16x16x32_bf16(ah[mi], bh[ni], acc[mi][ni], 0, 0, 0);
                        acc[mi][ni] = __builtin_amdgcn_mfma_f32_16x16x32_bf16(al[mi], bh[ni], acc[mi][ni], 0, 0, 0);
                        acc[mi][ni] = __builtin_amdgcn_mfma_f32_16x16x32_bf16(ah[mi], bl[ni], acc[mi][ni], 0, 0, 0);
                    }
                __builtin_amdgcn_s_setprio(0);
            }
            if (kc == capkc) {
                // A-tile cols q0g..q0g+31 ARE tem[f][q]: capture Gq x/h part.
                int q = lane & 31;
                int jg = (w << 1) | (lane >> 5);
                int lc = ((qt & 1) << 5) | q;
                int u8 = lc >> 3, byoff = (lc & 7) * 2;
                #pragma unroll
                for (int jj = 0; jj < 6; jj++) {
                    int j = jg * 6 + jj;
                    int off = j * 128 + (((u8) ^ (j & 7)) << 4) + byoff;
                    cxh[jj] = *(const u16*)(bo + off);
                    cxl[jj] = *(const u16*)(bo + 12288 + off);
                }
                asm volatile("s_waitcnt lgkmcnt(0)" ::: "memory");
                __builtin_amdgcn_sched_barrier(0);
            }
            __builtin_amdgcn_s_barrier();
        }

        // ---- merge kk-split partials (scratch = buf1 region, dead) ----
        {
            float* scratch = (float*)(lds + BUFSZ);
            if (kg == 0) {
                #pragma unroll
                for (int mi = 0; mi < 3; mi++)
                    #pragma unroll
                    for (int ni = 0; ni < 2; ni++) {
                        int c = wc * 32 + ni * 16 + (lane & 15);
                        int r0 = wr * 48 + mi * 16 + (lane >> 4) * 4;
                        *(f32x4*)&scratch[c * SCP + r0] = acc[mi][ni];
                    }
            }
            __syncthreads();
            if (kg == 1) {
                #pragma unroll
                for (int mi = 0; mi < 3; mi++)
                    #pragma unroll
                    for (int ni = 0; ni < 2; ni++) {
                        int c = wc * 32 + ni * 16 + (lane & 15);
                        int r0 = wr * 48 + mi * 16 + (lane >> 4) * 4;
                        acc[mi][ni] += *(const f32x4*)&scratch[c * SCP + r0];
                    }
            }
        }

        // ---- build Gq[32 q][288 j] (hi @0, lo @GQLO) — buf0 region ----
        {
            int q = lane & 31;
            int jg = (w << 1) | (lane >> 5);
            #pragma unroll
            for (int jj = 0; jj < 6; jj++) {
                int j = jg * 6 + jj;
                *(u16*)(lds + q * GQPB + j * 2) = cxh[jj];
                *(u16*)(lds + GQLO + q * GQPB + j * 2) = cxl[jj];
            }
        }
        if (kg == 1) {
            #pragma unroll
            for (int mi = 0; mi < 3; mi++)
                #pragma unroll
                for (int ni = 0; ni < 2; ni++) {
                    int c = wc * 32 + ni * 16 + (lane & 15);
                    int g = c >> 5, ql = c & 31;
                    int f0 = wr * 48 + mi * 16 + (lane >> 4) * 4;
                    int jd = 96 + g * 96 + f0;
                    short4v vh, vl;
                    #pragma unroll
                    for (int j = 0; j < 4; j++) {
                        float v = acc[mi][ni][j];
                        u16 hh = f2bf(v);
                        vh[j] = (short)hh;
                        vl[j] = (short)f2bf(v - bf2f(hh));
                    }
                    *(short4v*)(lds + ql * GQPB + jd * 2) = vh;
                    *(short4v*)(lds + GQLO + ql * GQPB + jd * 2) = vl;
                }
        }
        __syncthreads();

        // ---- phase 2: fea = Wcat @ Gq^T (256 o x 32 q, K=288) ----
        f32x4 a2[2][2];
        #pragma unroll
        for (int i = 0; i < 2; i++)
            #pragma unroll
            for (int j = 0; j < 2; j++) a2[i][j] = (f32x4){0.f, 0.f, 0.f, 0.f};

        const int kb8 = (lane >> 4) * 8;
        #pragma unroll
        for (int c = 0; c < 9; c++) {
            int j0 = c * 32;
            short8 wh[2], wl2[2], gh[2], gl[2];
            #pragma unroll
            for (int mi = 0; mi < 2; mi++) {
                int o = w * 32 + mi * 16 + (lane & 15);
                size_t so = (size_t)o * KJ + j0 + kb8;
                wh[mi]  = *(const short8*)&Wh[so];
                wl2[mi] = *(const short8*)&Wl[so];
            }
            #pragma unroll
            for (int ni = 0; ni < 2; ni++) {
                int q = ni * 16 + (lane & 15);
                int off = q * GQPB + (j0 + kb8) * 2;
                gh[ni] = *(const short8*)(lds + off);
                gl[ni] = *(const short8*)(lds + GQLO + off);
            }
            #pragma unroll
            for (int mi = 0; mi < 2; mi++)
                #pragma unroll
                for (int ni = 0; ni < 2; ni++) {
                    a2[mi][ni] = __builtin_amdgcn_mfma_f32_16x16x32_bf16(wh[mi],  gh[ni], a2[mi][ni], 0, 0, 0);
                    a2[mi][ni] = __builtin_amdgcn_mfma_f32_16x16x32_bf16(wl2[mi], gh[ni], a2[mi][ni], 0, 0, 0);
                    a2[mi][ni] = __builtin_amdgcn_mfma_f32_16x16x32_bf16(wh[mi],  gl[ni], a2[mi][ni], 0, 0, 0);
                }
        }
        __syncthreads();   // Gq dead; reuse LDS as FEA[o][33 floats]

        {
            float* FEAf = (float*)lds;
            #pragma unroll
            for (int mi = 0; mi < 2; mi++) {
                int o0 = w * 32 + mi * 16 + (lane >> 4) * 4;
                f32x4 bv = *(const f32x4*)&bias[o0];
                #pragma unroll
                for (int ni = 0; ni < 2; ni++) {
                    int q = ni * 16 + (lane & 15);
                    #pragma unroll
                    for (int j = 0; j < 4; j++)
                        FEAf[(o0 + j) * 33 + q] = a2[mi][ni][j] + bv[j];
                }
            }
        }
        __syncthreads();

        // ---- phase 3: LSTM update ----
        {
            const float* FEAf = (const float*)lds;
            int q = tid & 31, qg = q0g + q;
            int co0 = (tid >> 5) * 4;
            #pragma unroll
            for (int ii = 0; ii < 4; ii++) {
                int co = co0 + ii;
                float iv = FEAf[co * 33 + q];
                float jv = FEAf[(co + 64) * 33 + q];
                float fv = FEAf[(co + 128) * 33 + q];
                float ov = FEAf[(co + 192) * 33 + q];
                size_t cof = ((size_t)(bb * COUT + co)) * Nn + qg;
                float cc = cbuf[cof];
                float nc = cc * sigm(fv) + sigm(iv) * tanhf(jv);
                float nh = tanhf(nc) * sigm(ov);
                cbuf[cof] = nc;
                u16 hh = f2bf(nh);
                hout_hi[cof] = hh; hout_lo[cof] = f2bf(nh - bf2f(hh));
                outbuf[((size_t)(t * Bb + bb) * COUT + co) * Nn + qg] = nh;
            }
        }
        if (rep != reps - 1) __syncthreads();
    }
}

// ---------------- P3: outbuf (T,B,CO,N) -> out (B,CO,N,T) ----------------
__global__ __launch_bounds__(256) void k_out_t(const float* __restrict__ outbuf,
                                               float* __restrict__ out) {
    __shared__ float tile[64][65];
    int q0 = blockIdx.x * 64;
    int bo = blockIdx.y;
    int b = bo >> 6, o = bo & 63;
    int tid = threadIdx.x;
    #pragma unroll
    for (int i = 0; i < 16; i++) {
        int lin = i * 256 + tid;
        int tl = lin >> 6, ql = lin & 63;
        tile[tl][ql] = outbuf[(((size_t)tl * Bb + b) * COUT + o) * Nn + q0 + ql];
    }
    __syncthreads();
    #pragma unroll
    for (int i = 0; i < 16; i++) {
        int lin = i * 256 + tid;
        int ql = lin >> 6, tl = lin & 63;
        out[((size_t)bo * Nn + q0 + ql) * Tt + tl] = tile[tl][ql];
    }
}

extern "C" void kernel_launch(void* const* d_in, const int* in_sizes, int n_in,
                              void* d_out, int out_size, void* d_ws, size_t ws_size,
                              hipStream_t stream)
{
    const float* x    = (const float*)d_in[0];
    const float* adj  = (const float*)d_in[1];
    const float* W    = (const float*)d_in[2];
    const float* bias = (const float*)d_in[3];
    float* out = (float*)d_out;

    size_t off = 0;
    char* base = (char*)d_ws;
    auto take = [&](size_t bytes) -> void* {
        void* r = base + off;
        off += (bytes + 255) & ~(size_t)255;
        return r;
    };
    u16* bcat_hi = (u16*)take(2ull * 2 * Nn * Nn);
    u16* bcat_lo = (u16*)take(2ull * 2 * Nn * Nn);
    u16* adjT_hi = (u16*)take(2ull * Nn * Nn);
    u16* adjT_lo = (u16*)take(2ull * Nn * Nn);
    u16* xsf_hi  = (u16*)take(2ull * Tt * Bb * CIN * Nn);
    u16* xsf_lo  = (u16*)take(2ull * Tt * Bb * CIN * Nn);
    u16* hfA_hi  = (u16*)take(2ull * Bb * COUT * Nn);
    u16* hfA_lo  = (u16*)take(2ull * Bb * COUT * Nn);
    u16* hfB_hi  = (u16*)take(2ull * Bb * COUT * Nn);
    u16* hfB_lo  = (u16*)take(2ull * Bb * COUT * Nn);
    float* cbuf  = (float*)take(4ull * Bb * COUT * Nn);
    u16* Wc_hi   = (u16*)take(2ull * G4 * KJ);
    u16* Wc_lo   = (u16*)take(2ull * G4 * KJ);
    float* outbuf = (float*)take(4ull * (size_t)Tt * Bb * COUT * Nn);
    // probe scratch
    u16* prH_hi  = (u16*)take(2ull * Bb * COUT * Nn);
    u16* prH_lo  = (u16*)take(2ull * Bb * COUT * Nn);
    float* prC   = (float*)take(4ull * Bb * COUT * Nn);
    float* prOut = (float*)take(4ull * Bb * COUT * Nn);

    if (off > ws_size) {
        float v = (float)(ws_size >> 20);
        k_fill<<<dim3((out_size + 255) / 256), 256, 0, stream>>>(out, out_size, v);
        return;
    }

    hipMemsetAsync(hfA_hi, 0, 2ull * Bb * COUT * Nn, stream);
    hipMemsetAsync(hfA_lo, 0, 2ull * Bb * COUT * Nn, stream);
    hipMemsetAsync(cbuf, 0, 4ull * Bb * COUT * Nn, stream);
    hipMemsetAsync(prC,  0, 4ull * Bb * COUT * Nn, stream);

    k_adj_split<<<dim3((Nn * Nn) / 256), 256, 0, stream>>>(adj, bcat_hi, bcat_lo);
    k_adj_t<<<dim3(16, 16), 256, 0, stream>>>(adj, adjT_hi, adjT_lo);
    k_l2<<<dim3(16, 16), 256, 0, stream>>>(bcat_hi, bcat_lo, adjT_hi, adjT_lo,
                                           bcat_hi + (size_t)Nn * Nn, bcat_lo + (size_t)Nn * Nn);
    k_w_split<<<dim3((G4 * KJ) / 256), 256, 0, stream>>>(W, Wc_hi, Wc_lo);
    k_x_split<<<dim3(Nn / 64, Bb * CIN), 256, 0, stream>>>(x, xsf_hi, xsf_lo);

    // probe: 8 reps of the step body into scratch (appears in rocprof top-5)
    k_step<<<dim3(512), 512, 0, stream>>>(0, 8,
        xsf_hi, xsf_lo, hfA_hi, hfA_lo, prH_hi, prH_lo,
        bcat_hi, bcat_lo, Wc_hi, Wc_lo, bias, prC, prOut);

    for (int t = 0; t < Tt; t++) {
        const u16* hi_in  = (t & 1) ? hfB_hi : hfA_hi;
        const u16* lo_in  = (t & 1) ? hfB_lo : hfA_lo;
        u16* hi_out = (t & 1) ? hfA_hi : hfB_hi;
        u16* lo_out = (t & 1) ? hfA_lo : hfB_lo;
        k_step<<<dim3(512), 512, 0, stream>>>(t, 1,
            xsf_hi, xsf_lo, hi_in, lo_in, hi_out, lo_out,
            bcat_hi, bcat_lo, Wc_hi, Wc_lo, bias, cbuf, outbuf);
    }
    k_out_t<<<dim3(Nn / 64, Bb * COUT), 256, 0, stream>>>(outbuf, out);
}

// Round 11
// 2474.117 us; speedup vs baseline: 4.4570x; 4.4570x over previous
//
#include <hip/hip_runtime.h>
#include <stdint.h>

// ST_BLOCK fused, R11 = byte-identical R7 step body (best measured: 2514us) with
// the ONLY change being the h race fix: hin (const, staged) / hout (written) split
// + hfA/hfB ping-pong in the launcher. No reps loop, no probe, 2D grid, 2 blk/CU.

#define Bb   16
#define CIN  32
#define COUT 64
#define Nn   1024
#define Tt   64
#define Ff   96
#define G4   256
#define KJ   288

#define BUFSZ 40960     // A hi 12K | A lo 12K | B hi 8K | B lo 8K
#define GQPB  624       // Gq row pitch bytes (312 u16)
#define GQLO  19968     // Gq_lo offset (32*624)
#define SCP   100       // merge scratch pitch (floats); scratch at lds+BUFSZ

typedef unsigned short u16;
typedef short short8 __attribute__((ext_vector_type(8)));
typedef short short4v __attribute__((ext_vector_type(4)));
typedef float f32x4 __attribute__((ext_vector_type(4)));

static __device__ __forceinline__ u16 f2bf(float f) {
    union { float f; uint32_t u; } v; v.f = f;
    uint32_t r = v.u + 0x7FFFu + ((v.u >> 16) & 1u);
    return (u16)(r >> 16);
}
static __device__ __forceinline__ float bf2f(u16 h) {
    union { uint32_t u; float f; } v; v.u = ((uint32_t)h) << 16;
    return v.f;
}
static __device__ __forceinline__ float sigm(float x) { return 1.0f / (1.0f + expf(-x)); }

static __device__ __forceinline__ void gload16(const void* g, void* l) {
    __builtin_amdgcn_global_load_lds(
        (const __attribute__((address_space(1))) void*)g,
        (__attribute__((address_space(3))) void*)l, 16, 0, 0);
}

// ---------------- diagnostics ----------------
__global__ void k_fill(float* out, int n, float v) {
    int i = blockIdx.x * 256 + threadIdx.x;
    if (i < n) out[i] = v;
}

// ---------------- P0: adj -> bcat rows 0..1023 ----------------
__global__ __launch_bounds__(256) void k_adj_split(const float* __restrict__ adj,
                                                   u16* __restrict__ hi, u16* __restrict__ lo) {
    int i = blockIdx.x * 256 + threadIdx.x;
    float v = adj[i];
    u16 h = f2bf(v);
    hi[i] = h; lo[i] = f2bf(v - bf2f(h));
}

// ---------------- P0b: adjT split ----------------
__global__ __launch_bounds__(256) void k_adj_t(const float* __restrict__ adj,
                                               u16* __restrict__ th, u16* __restrict__ tl_) {
    __shared__ float tile[64][65];
    int m0 = blockIdx.x * 64, n0 = blockIdx.y * 64;
    int tid = threadIdx.x;
    #pragma unroll
    for (int i = 0; i < 16; i++) {
        int lin = i * 256 + tid;
        int ml = lin >> 6, nl = lin & 63;
        tile[ml][nl] = adj[(size_t)(m0 + ml) * Nn + n0 + nl];
    }
    __syncthreads();
    #pragma unroll
    for (int i = 0; i < 16; i++) {
        int lin = i * 256 + tid;
        int nl = lin >> 6, ml = lin & 63;
        float v = tile[ml][nl];
        u16 h = f2bf(v);
        size_t off = (size_t)(n0 + nl) * Nn + m0 + ml;
        th[off] = h; tl_[off] = f2bf(v - bf2f(h));
    }
}

// ---------------- P0c: L2 = 2*adj@adj - I -> bcat rows 1024+ ----------------
__global__ __launch_bounds__(256) void k_l2(
    const u16* __restrict__ a_hi, const u16* __restrict__ a_lo,
    const u16* __restrict__ bt_hi, const u16* __restrict__ bt_lo,
    u16* __restrict__ o_hi, u16* __restrict__ o_lo)
{
    __shared__ u16 Ah[64][40], Al[64][40], Bh[64][40], Bl[64][40];
    const int tid = threadIdx.x, lane = tid & 63, w = tid >> 6;
    const int wm = (w >> 1) * 32, wn = (w & 1) * 32;
    const int r0 = blockIdx.x * 64, q0 = blockIdx.y * 64;
    const int srow = tid >> 2, scol = (tid & 3) * 8;
    const u16* arh = a_hi + (size_t)(r0 + srow) * Nn;
    const u16* arl = a_lo + (size_t)(r0 + srow) * Nn;
    const u16* brh = bt_hi + (size_t)(q0 + srow) * Nn;
    const u16* brl = bt_lo + (size_t)(q0 + srow) * Nn;

    f32x4 acc[2][2];
    #pragma unroll
    for (int i = 0; i < 2; i++)
        #pragma unroll
        for (int j = 0; j < 2; j++) acc[i][j] = (f32x4){0.f, 0.f, 0.f, 0.f};

    for (int k0 = 0; k0 < Nn; k0 += 32) {
        __syncthreads();
        *(short8*)&Ah[srow][scol] = *(const short8*)&arh[k0 + scol];
        *(short8*)&Al[srow][scol] = *(const short8*)&arl[k0 + scol];
        *(short8*)&Bh[srow][scol] = *(const short8*)&brh[k0 + scol];
        *(short8*)&Bl[srow][scol] = *(const short8*)&brl[k0 + scol];
        __syncthreads();
        const int kb = (lane >> 4) * 8;
        short8 ah[2], al[2], bh[2], bl[2];
        #pragma unroll
        for (int mi = 0; mi < 2; mi++) {
            int row = wm + mi * 16 + (lane & 15);
            ah[mi] = *(const short8*)&Ah[row][kb];
            al[mi] = *(const short8*)&Al[row][kb];
        }
        #pragma unroll
        for (int ni = 0; ni < 2; ni++) {
            int col = wn + ni * 16 + (lane & 15);
            bh[ni] = *(const short8*)&Bh[col][kb];
            bl[ni] = *(const short8*)&Bl[col][kb];
        }
        #pragma unroll
        for (int mi = 0; mi < 2; mi++)
            #pragma unroll
            for (int ni = 0; ni < 2; ni++) {
                acc[mi][ni] = __builtin_amdgcn_mfma_f32_16x16x32_bf16(ah[mi], bh[ni], acc[mi][ni], 0, 0, 0);
                acc[mi][ni] = __builtin_amdgcn_mfma_f32_16x16x32_bf16(al[mi], bh[ni], acc[mi][ni], 0, 0, 0);
                acc[mi][ni] = __builtin_amdgcn_mfma_f32_16x16x32_bf16(ah[mi], bl[ni], acc[mi][ni], 0, 0, 0);
            }
    }
    #pragma unroll
    for (int mi = 0; mi < 2; mi++)
        #pragma unroll
        for (int ni = 0; ni < 2; ni++)
            #pragma unroll
            for (int j = 0; j < 4; j++) {
                int rr = r0 + wm + mi * 16 + (lane >> 4) * 4 + j;
                int qq = q0 + wn + ni * 16 + (lane & 15);
                float v = 2.f * acc[mi][ni][j] - ((rr == qq) ? 1.f : 0.f);
                size_t off = (size_t)rr * Nn + qq;
                u16 hh = f2bf(v);
                o_hi[off] = hh; o_lo[off] = f2bf(v - bf2f(hh));
            }
}

// ---------------- P2: W reorder+split ----------------
__global__ __launch_bounds__(256) void k_w_split(const float* __restrict__ W,
                                                 u16* __restrict__ hi, u16* __restrict__ lo) {
    int idx = blockIdx.x * 256 + threadIdx.x;
    int o = idx / KJ, j = idx - o * KJ;
    int k = j / Ff, f = j - k * Ff;
    float v = W[(size_t)o * KJ + f * 3 + k];
    u16 h = f2bf(v);
    hi[idx] = h; lo[idx] = f2bf(v - bf2f(h));
}

// ---------------- P1: x (B,CIN,N,T) -> xsf (T,B,CIN,N) split, vectorized stores ----------------
__global__ __launch_bounds__(256) void k_x_split(const float* __restrict__ x,
        u16* __restrict__ xf_hi, u16* __restrict__ xf_lo) {
    __shared__ float tile[64][65];
    int n0 = blockIdx.x * 64;
    int bc = blockIdx.y;
    const float* src = x + (size_t)bc * Nn * Tt;
    int tid = threadIdx.x;
    #pragma unroll
    for (int i = 0; i < 16; i++) {
        int lin = i * 256 + tid;
        int nl = lin >> 6, tl = lin & 63;
        tile[nl][tl] = src[(size_t)(n0 + nl) * Tt + tl];
    }
    __syncthreads();
    int b = bc >> 5, ch = bc & 31;
    #pragma unroll
    for (int i = 0; i < 2; i++) {
        int item = i * 256 + tid;
        int tl = item >> 3, oct = item & 7;
        short8 vh, vl;
        #pragma unroll
        for (int m = 0; m < 8; m++) {
            float v = tile[oct * 8 + m][tl];
            u16 h = f2bf(v);
            vh[m] = (short)h;
            vl[m] = (short)f2bf(v - bf2f(h));
        }
        size_t off = (((size_t)tl * Bb + b) * CIN + ch) * Nn + n0 + oct * 8;
        *(short8*)&xf_hi[off] = vh;
        *(short8*)&xf_lo[off] = vl;
    }
}

// ---------------- K: fused step ----------------
// grid (32 q-tiles, 16 b), 512 threads, LDS 81920 -> 2 blocks/CU.
__global__ __launch_bounds__(512, 4) void k_step(
    int t,
    const u16* __restrict__ xsf_hi, const u16* __restrict__ xsf_lo,
    const u16* __restrict__ hin_hi, const u16* __restrict__ hin_lo,
    u16* __restrict__ hout_hi, u16* __restrict__ hout_lo,
    const u16* __restrict__ bcat_hi, const u16* __restrict__ bcat_lo,
    const u16* __restrict__ Wh, const u16* __restrict__ Wl,
    const float* __restrict__ bias, float* __restrict__ cbuf,
    float* __restrict__ outbuf)
{
    __shared__ __attribute__((aligned(16))) char lds[81920];
    const int tid = threadIdx.x, lane = tid & 63, w = tid >> 6;
    const int bx = blockIdx.x;           // q-tile (32 wide)
    const int q0g = bx * 32;
    const int bb = blockIdx.y;

    // ----- staging decode: 5 x 16B global_load_lds per thread per chunk -----
    // units: [0,768)=A_hi 96x8, [768,1536)=A_lo, [1536,2048)=B_hi 64x8, [2048,2560)=B_lo
    const u16* srcb[5];
    #pragma unroll
    for (int i = 0; i < 5; i++) {
        int u = i * 512 + tid;
        if (u < 1536) {
            int hl = (u >= 768) ? 1 : 0;
            int r = (u - hl * 768) >> 3, c8 = u & 7;
            const u16* p;
            if (r < CIN) p = (hl ? xsf_lo : xsf_hi) + (size_t)((t * Bb + bb) * CIN + r) * Nn;
            else         p = (hl ? hin_lo : hin_hi) + (size_t)(bb * COUT + r - CIN) * Nn;
            srcb[i] = p + (c8 ^ (r & 7)) * 8;
        } else {
            int v = u - 1536;
            int hl = v >> 9;
            int r = (v & 511) >> 3, c8 = v & 7;
            int grow = q0g + (r & 31) + ((r >= 32) ? Nn : 0);   // 0..31 adj, 32..63 L2
            srcb[i] = (hl ? bcat_lo : bcat_hi) + (size_t)grow * Nn + (c8 ^ (r & 7)) * 8;
        }
    }

    // ================= phase 1: [g1|g2] = tem @ Bcat^T (96 x 64) =================
    // kk-split: waves 0-3 do K-units 0-3 of each chunk, waves 4-7 units 4-7.
    const int kg = w >> 2;
    const int wsub = w & 3;
    const int wr = wsub >> 1, wc = wsub & 1;
    const int ksw = kg * 4 + (lane >> 4);   // 16B-unit index within 64-wide chunk

    f32x4 acc[3][2];
    #pragma unroll
    for (int i = 0; i < 3; i++)
        #pragma unroll
        for (int j = 0; j < 2; j++) acc[i][j] = (f32x4){0.f, 0.f, 0.f, 0.f};

    u16 cxh[6], cxl[6];
    #pragma unroll
    for (int i = 0; i < 6; i++) { cxh[i] = 0; cxl[i] = 0; }
    const int capkc = bx >> 1;

    // prologue: chunk 0 -> buf0
    #pragma unroll
    for (int i = 0; i < 5; i++)
        gload16(srcb[i], lds + (i * 512 + tid) * 16);

    for (int kc = 0; kc < 16; kc++) {
        if (kc < 15) {
            char* nb = lds + ((kc + 1) & 1) * BUFSZ;
            const int k0 = (kc + 1) * 64;
            #pragma unroll
            for (int i = 0; i < 5; i++)
                gload16(srcb[i] + k0, nb + (i * 512 + tid) * 16);
            asm volatile("s_waitcnt vmcnt(5)" ::: "memory");
        } else {
            asm volatile("s_waitcnt vmcnt(0)" ::: "memory");
        }
        __builtin_amdgcn_s_barrier();
        const char* bo = lds + (kc & 1) * BUFSZ;
        {
            short8 ah[3], al[3], bh[2], bl[2];
            #pragma unroll
            for (int mi = 0; mi < 3; mi++) {
                int r = wr * 48 + mi * 16 + (lane & 15);
                int off = r * 128 + ((ksw ^ (r & 7)) << 4);
                ah[mi] = *(const short8*)(bo + off);
                al[mi] = *(const short8*)(bo + 12288 + off);
            }
            #pragma unroll
            for (int ni = 0; ni < 2; ni++) {
                int rb = wc * 32 + ni * 16 + (lane & 15);
                int off = 24576 + rb * 128 + ((ksw ^ (rb & 7)) << 4);
                bh[ni] = *(const short8*)(bo + off);
                bl[ni] = *(const short8*)(bo + 8192 + off);
            }
            __builtin_amdgcn_s_setprio(1);
            #pragma unroll
            for (int mi = 0; mi < 3; mi++)
                #pragma unroll
                for (int ni = 0; ni < 2; ni++) {
                    acc[mi][ni] = __builtin_amdgcn_mfma_f32_16x16x32_bf16(ah[mi], bh[ni], acc[mi][ni], 0, 0, 0);
                    acc[mi][ni] = __builtin_amdgcn_mfma_f32_16x16x32_bf16(al[mi], bh[ni], acc[mi][ni], 0, 0, 0);
                    acc[mi][ni] = __builtin_amdgcn_mfma_f32_16x16x32_bf16(ah[mi], bl[ni], acc[mi][ni], 0, 0, 0);
                }
            __builtin_amdgcn_s_setprio(0);
        }
        if (kc == capkc) {
            // A-tile cols q0g..q0g+31 ARE tem[f][q]: capture Gq x/h part to regs.
            int q = lane & 31;
            int jg = (w << 1) | (lane >> 5);
            int lc = ((bx & 1) << 5) | q;
            int u8 = lc >> 3, byoff = (lc & 7) * 2;
            #pragma unroll
            for (int jj = 0; jj < 6; jj++) {
                int j = jg * 6 + jj;
                int off = j * 128 + (((u8) ^ (j & 7)) << 4) + byoff;
                cxh[jj] = *(const u16*)(bo + off);
                cxl[jj] = *(const u16*)(bo + 12288 + off);
            }
            asm volatile("s_waitcnt lgkmcnt(0)" ::: "memory");
            __builtin_amdgcn_sched_barrier(0);
        }
        __builtin_amdgcn_s_barrier();
    }

    // ================= merge kk-split partials (scratch = buf1 region, dead) =================
    {
        float* scratch = (float*)(lds + BUFSZ);
        if (kg == 0) {
            #pragma unroll
            for (int mi = 0; mi < 3; mi++)
                #pragma unroll
                for (int ni = 0; ni < 2; ni++) {
                    int c = wc * 32 + ni * 16 + (lane & 15);
                    int r0 = wr * 48 + mi * 16 + (lane >> 4) * 4;
                    *(f32x4*)&scratch[c * SCP + r0] = acc[mi][ni];
                }
        }
        __syncthreads();
        if (kg == 1) {
            #pragma unroll
            for (int mi = 0; mi < 3; mi++)
                #pragma unroll
                for (int ni = 0; ni < 2; ni++) {
                    int c = wc * 32 + ni * 16 + (lane & 15);
                    int r0 = wr * 48 + mi * 16 + (lane >> 4) * 4;
                    acc[mi][ni] += *(const f32x4*)&scratch[c * SCP + r0];
                }
        }
    }

    // ================= build Gq[32 q][288 j] (hi @0, lo @GQLO) — buf0 region =================
    {
        int q = lane & 31;
        int jg = (w << 1) | (lane >> 5);
        #pragma unroll
        for (int jj = 0; jj < 6; jj++) {
            int j = jg * 6 + jj;
            *(u16*)(lds + q * GQPB + j * 2) = cxh[jj];
            *(u16*)(lds + GQLO + q * GQPB + j * 2) = cxl[jj];
        }
    }
    if (kg == 1) {
        #pragma unroll
        for (int mi = 0; mi < 3; mi++)
            #pragma unroll
            for (int ni = 0; ni < 2; ni++) {
                int c = wc * 32 + ni * 16 + (lane & 15);
                int g = c >> 5, ql = c & 31;
                int f0 = wr * 48 + mi * 16 + (lane >> 4) * 4;
                int jd = 96 + g * 96 + f0;
                short4v vh, vl;
                #pragma unroll
                for (int j = 0; j < 4; j++) {
                    float v = acc[mi][ni][j];
                    u16 hh = f2bf(v);
                    vh[j] = (short)hh;
                    vl[j] = (short)f2bf(v - bf2f(hh));
                }
                *(short4v*)(lds + ql * GQPB + jd * 2) = vh;
                *(short4v*)(lds + GQLO + ql * GQPB + jd * 2) = vl;
            }
    }
    __syncthreads();

    // ================= phase 2: fea = Wcat @ Gq^T (256 o x 32 q, K=288) =================
    f32x4 a2[2][2];
    #pragma unroll
    for (int i = 0; i < 2; i++)
        #pragma unroll
        for (int j = 0; j < 2; j++) a2[i][j] = (f32x4){0.f, 0.f, 0.f, 0.f};

    const int kb8 = (lane >> 4) * 8;
    #pragma unroll
    for (int c = 0; c < 9; c++) {
        int j0 = c * 32;
        short8 wh[2], wl2[2], gh[2], gl[2];
        #pragma unroll
        for (int mi = 0; mi < 2; mi++) {
            int o = w * 32 + mi * 16 + (lane & 15);
            size_t so = (size_t)o * KJ + j0 + kb8;
            wh[mi]  = *(const short8*)&Wh[so];
            wl2[mi] = *(const short8*)&Wl[so];
        }
        #pragma unroll
        for (int ni = 0; ni < 2; ni++) {
            int q = ni * 16 + (lane & 15);
            int off = q * GQPB + (j0 + kb8) * 2;
            gh[ni] = *(const short8*)(lds + off);
            gl[ni] = *(const short8*)(lds + GQLO + off);
        }
        #pragma unroll
        for (int mi = 0; mi < 2; mi++)
            #pragma unroll
            for (int ni = 0; ni < 2; ni++) {
                a2[mi][ni] = __builtin_amdgcn_mfma_f32_16x16x32_bf16(wh[mi],  gh[ni], a2[mi][ni], 0, 0, 0);
                a2[mi][ni] = __builtin_amdgcn_mfma_f32_16x16x32_bf16(wl2[mi], gh[ni], a2[mi][ni], 0, 0, 0);
                a2[mi][ni] = __builtin_amdgcn_mfma_f32_16x16x32_bf16(wh[mi],  gl[ni], a2[mi][ni], 0, 0, 0);
            }
    }
    __syncthreads();   // Gq dead; reuse LDS as FEA[o][33 floats]

    {
        float* FEAf = (float*)lds;
        #pragma unroll
        for (int mi = 0; mi < 2; mi++) {
            int o0 = w * 32 + mi * 16 + (lane >> 4) * 4;
            f32x4 bv = *(const f32x4*)&bias[o0];
            #pragma unroll
            for (int ni = 0; ni < 2; ni++) {
                int q = ni * 16 + (lane & 15);
                #pragma unroll
                for (int j = 0; j < 4; j++)
                    FEAf[(o0 + j) * 33 + q] = a2[mi][ni][j] + bv[j];
            }
        }
    }
    __syncthreads();

    // ================= phase 3: LSTM update =================
    {
        const float* FEAf = (const float*)lds;
        int q = tid & 31, qg = q0g + q;
        int co0 = (tid >> 5) * 4;
        #pragma unroll
        for (int ii = 0; ii < 4; ii++) {
            int co = co0 + ii;
            float iv = FEAf[co * 33 + q];
            float jv = FEAf[(co + 64) * 33 + q];
            float fv = FEAf[(co + 128) * 33 + q];
            float ov = FEAf[(co + 192) * 33 + q];
            size_t cof = ((size_t)(bb * COUT + co)) * Nn + qg;
            float cc = cbuf[cof];
            float nc = cc * sigm(fv) + sigm(iv) * tanhf(jv);
            float nh = tanhf(nc) * sigm(ov);
            cbuf[cof] = nc;
            u16 hh = f2bf(nh);
            hout_hi[cof] = hh; hout_lo[cof] = f2bf(nh - bf2f(hh));
            outbuf[((size_t)(t * Bb + bb) * COUT + co) * Nn + qg] = nh;
        }
    }
}

// ---------------- P3: outbuf (T,B,CO,N) -> out (B,CO,N,T) ----------------
__global__ __launch_bounds__(256) void k_out_t(const float* __restrict__ outbuf,
                                               float* __restrict__ out) {
    __shared__ float tile[64][65];
    int q0 = blockIdx.x * 64;
    int bo = blockIdx.y;
    int b = bo >> 6, o = bo & 63;
    int tid = threadIdx.x;
    #pragma unroll
    for (int i = 0; i < 16; i++) {
        int lin = i * 256 + tid;
        int tl = lin >> 6, ql = lin & 63;
        tile[tl][ql] = outbuf[(((size_t)tl * Bb + b) * COUT + o) * Nn + q0 + ql];
    }
    __syncthreads();
    #pragma unroll
    for (int i = 0; i < 16; i++) {
        int lin = i * 256 + tid;
        int ql = lin >> 6, tl = lin & 63;
        out[((size_t)bo * Nn + q0 + ql) * Tt + tl] = tile[tl][ql];
    }
}

extern "C" void kernel_launch(void* const* d_in, const int* in_sizes, int n_in,
                              void* d_out, int out_size, void* d_ws, size_t ws_size,
                              hipStream_t stream)
{
    const float* x    = (const float*)d_in[0];
    const float* adj  = (const float*)d_in[1];
    const float* W    = (const float*)d_in[2];
    const float* bias = (const float*)d_in[3];
    float* out = (float*)d_out;

    size_t off = 0;
    char* base = (char*)d_ws;
    auto take = [&](size_t bytes) -> void* {
        void* r = base + off;
        off += (bytes + 255) & ~(size_t)255;
        return r;
    };
    u16* bcat_hi = (u16*)take(2ull * 2 * Nn * Nn);
    u16* bcat_lo = (u16*)take(2ull * 2 * Nn * Nn);
    u16* adjT_hi = (u16*)take(2ull * Nn * Nn);
    u16* adjT_lo = (u16*)take(2ull * Nn * Nn);
    u16* xsf_hi  = (u16*)take(2ull * Tt * Bb * CIN * Nn);
    u16* xsf_lo  = (u16*)take(2ull * Tt * Bb * CIN * Nn);
    u16* hfA_hi  = (u16*)take(2ull * Bb * COUT * Nn);
    u16* hfA_lo  = (u16*)take(2ull * Bb * COUT * Nn);
    u16* hfB_hi  = (u16*)take(2ull * Bb * COUT * Nn);
    u16* hfB_lo  = (u16*)take(2ull * Bb * COUT * Nn);
    float* cbuf  = (float*)take(4ull * Bb * COUT * Nn);
    u16* Wc_hi   = (u16*)take(2ull * G4 * KJ);
    u16* Wc_lo   = (u16*)take(2ull * G4 * KJ);
    float* outbuf = (float*)take(4ull * (size_t)Tt * Bb * COUT * Nn);

    if (off > ws_size) {
        float v = (float)(ws_size >> 20);
        k_fill<<<dim3((out_size + 255) / 256), 256, 0, stream>>>(out, out_size, v);
        return;
    }

    hipMemsetAsync(hfA_hi, 0, 2ull * Bb * COUT * Nn, stream);
    hipMemsetAsync(hfA_lo, 0, 2ull * Bb * COUT * Nn, stream);
    hipMemsetAsync(cbuf, 0, 4ull * Bb * COUT * Nn, stream);

    k_adj_split<<<dim3((Nn * Nn) / 256), 256, 0, stream>>>(adj, bcat_hi, bcat_lo);
    k_adj_t<<<dim3(16, 16), 256, 0, stream>>>(adj, adjT_hi, adjT_lo);
    k_l2<<<dim3(16, 16), 256, 0, stream>>>(bcat_hi, bcat_lo, adjT_hi, adjT_lo,
                                           bcat_hi + (size_t)Nn * Nn, bcat_lo + (size_t)Nn * Nn);
    k_w_split<<<dim3((G4 * KJ) / 256), 256, 0, stream>>>(W, Wc_hi, Wc_lo);
    k_x_split<<<dim3(Nn / 64, Bb * CIN), 256, 0, stream>>>(x, xsf_hi, xsf_lo);

    for (int t = 0; t < Tt; t++) {
        const u16* hi_in  = (t & 1) ? hfB_hi : hfA_hi;
        const u16* lo_in  = (t & 1) ? hfB_lo : hfA_lo;
        u16* hi_out = (t & 1) ? hfA_hi : hfB_hi;
        u16* lo_out = (t & 1) ? hfA_lo : hfB_lo;
        k_step<<<dim3(32, 16), 512, 0, stream>>>(t,
            xsf_hi, xsf_lo, hi_in, lo_in, hi_out, lo_out,
            bcat_hi, bcat_lo, Wc_hi, Wc_lo,
            bias, cbuf, outbuf);
    }
    k_out_t<<<dim3(Nn / 64, Bb * COUT), 256, 0, stream>>>(outbuf, out);
}